// Round 6
// baseline (174.321 us; speedup 1.0000x reference)
//
#include <hip/hip_runtime.h>
#include <hip/hip_bf16.h>
#include <cstddef>

typedef __attribute__((ext_vector_type(8)))  short bf16x8;
typedef __attribute__((ext_vector_type(4)))  short bf16x4;
typedef __attribute__((ext_vector_type(4)))  float f32x4;
typedef __attribute__((ext_vector_type(16))) float f32x16;

constexpr int Bn = 4, Ln = 2048, Dn = 512, Hn = 8, DKn = 64, Mtot = 8192;
// 1/sqrt(DK) * log2(e): softmax computed in exp2 domain
constexpr float QSCALE = 0.125f * 1.44269504088896341f;

// hardware packed fp32->bf16 (RNE), 2 values per instruction
__device__ inline unsigned cvt_pk_bf16(float lo, float hi) {
    unsigned r;
    asm("v_cvt_pk_bf16_f32 %0, %1, %2" : "=v"(r) : "v"(lo), "v"(hi));
    return r;
}
// scalar fp32->bf16 RNE (finite inputs only)
__device__ inline short f2bf(float x) {
    union { float f; unsigned u; } v; v.f = x;
    unsigned r = v.u + 0x7fffu + ((v.u >> 16) & 1u);
    return (short)(r >> 16);
}

// ---------------------------------------------------------------------------
// Kernel 0: mask -> additive f32 (-1e30 / 0)
// ---------------------------------------------------------------------------
__global__ __launch_bounds__(256) void mask_prep(
    const int* __restrict__ masks, float* __restrict__ maskF)
{
    int i = blockIdx.x * 256 + threadIdx.x;
    if (i < Bn * Ln) maskF[i] = (masks[i] == 0) ? -1e30f : 0.f;
}

// ---------------------------------------------------------------------------
// Kernel 1: QKV projection, bf16 MFMA.  C = X @ W^T + b.
// Q pre-scaled by QSCALE.  Q,K: bf16 [b][h][l][dk]; V: bf16 [b][h][dk][l].
// ---------------------------------------------------------------------------
__global__ __launch_bounds__(256) void qkv_proj_mfma(
    const float* __restrict__ q, const float* __restrict__ k, const float* __restrict__ v,
    const float* __restrict__ wq, const float* __restrict__ wk, const float* __restrict__ wv,
    const float* __restrict__ bq, const float* __restrict__ bk, const float* __restrict__ bv,
    short* __restrict__ Qh, short* __restrict__ Kh, short* __restrict__ Vt)
{
    const int p = blockIdx.z;
    const float* X    = (p == 0) ? q  : (p == 1) ? k  : v;
    const float* W    = (p == 0) ? wq : (p == 1) ? wk : wv;
    const float* bias = (p == 0) ? bq : (p == 1) ? bk : bv;
    short*       O    = (p == 0) ? Qh : (p == 1) ? Kh : Vt;
    const float scl   = (p == 0) ? QSCALE : 1.0f;

    __shared__ short As[128 * 72];
    __shared__ short Bs[128 * 72];

    const int tid  = threadIdx.x;
    const int lane = tid & 63, w = tid >> 6;
    const int wr = w >> 1, wc = w & 1;
    const int l16 = lane & 15, g = lane >> 4;
    const int m0 = blockIdx.x * 128, n0 = blockIdx.y * 128;

    f32x4 acc[4][4];
    #pragma unroll
    for (int i = 0; i < 4; ++i)
        #pragma unroll
        for (int j = 0; j < 4; ++j)
            acc[i][j] = (f32x4){0.f, 0.f, 0.f, 0.f};

    for (int k0 = 0; k0 < Dn; k0 += 64) {
        #pragma unroll
        for (int f = 0; f < 8; ++f) {
            int lin = tid + 256 * f;
            int row = lin >> 4, c4 = lin & 15;
            float4 xv = *(const float4*)&X[(size_t)(m0 + row) * Dn + k0 + c4 * 4];
            uint2 xp = {cvt_pk_bf16(xv.x, xv.y), cvt_pk_bf16(xv.z, xv.w)};
            *(uint2*)&As[row * 72 + c4 * 4] = xp;
            float4 wv4 = *(const float4*)&W[(size_t)(n0 + row) * Dn + k0 + c4 * 4];
            uint2 wp = {cvt_pk_bf16(wv4.x, wv4.y), cvt_pk_bf16(wv4.z, wv4.w)};
            *(uint2*)&Bs[row * 72 + c4 * 4] = wp;
        }
        __syncthreads();

        bf16x8 af[4][2], bfv[4][2];
        #pragma unroll
        for (int i = 0; i < 4; ++i)
            #pragma unroll
            for (int c = 0; c < 2; ++c)
                af[i][c] = *(const bf16x8*)&As[(wr * 64 + i * 16 + l16) * 72 + c * 32 + g * 8];
        #pragma unroll
        for (int j = 0; j < 4; ++j)
            #pragma unroll
            for (int c = 0; c < 2; ++c)
                bfv[j][c] = *(const bf16x8*)&Bs[(wc * 64 + j * 16 + l16) * 72 + c * 32 + g * 8];

        #pragma unroll
        for (int i = 0; i < 4; ++i)
            #pragma unroll
            for (int j = 0; j < 4; ++j) {
                acc[i][j] = __builtin_amdgcn_mfma_f32_16x16x32_bf16(af[i][0], bfv[j][0], acc[i][j], 0, 0, 0);
                acc[i][j] = __builtin_amdgcn_mfma_f32_16x16x32_bf16(af[i][1], bfv[j][1], acc[i][j], 0, 0, 0);
            }
        __syncthreads();
    }

    const int bb = m0 >> 11;
    #pragma unroll
    for (int i = 0; i < 4; ++i) {
        #pragma unroll
        for (int j = 0; j < 4; ++j) {
            int n  = n0 + wc * 64 + j * 16 + l16;
            int h  = n >> 6, dk = n & 63;
            float bval = bias[n];
            #pragma unroll
            for (int r = 0; r < 4; ++r) {
                int m  = m0 + wr * 64 + i * 16 + g * 4 + r;
                int lq = m & (Ln - 1);
                short val = f2bf((acc[i][j][r] + bval) * scl);
                if (p < 2)
                    O[(((size_t)bb * Hn + h) * Ln + lq) * DKn + dk] = val;
                else
                    O[(((size_t)bb * Hn + h) * DKn + dk) * Ln + lq] = val;
            }
        }
    }
}

// ---------------------------------------------------------------------------
// Kernel 2: flash attention, 32x32x16 bf16 MFMA, swapped QK^T, O^T output,
// defer-max, MFMA row sums, dbuf K/V staging, XCD-swizzled grid.
// 2 waves x 32 q = 64 q/block, KV-tile 64. grid 1024 flat, block 128.
// ---------------------------------------------------------------------------
__global__ __launch_bounds__(128) void attn_mfma(
    const short* __restrict__ Qh, const short* __restrict__ Kh, const short* __restrict__ Vt,
    const float* __restrict__ maskF, short* __restrict__ Ctx)
{
    __shared__ short Ks[2][64 * 64];
    __shared__ short Vs[2][64 * 64];
    __shared__ short Pl[2][32 * 64];

    const int tid  = threadIdx.x;
    const int lane = tid & 63, w = tid >> 6;          // w in {0,1}
    const int q32 = lane & 31, hi = lane >> 5;
    // XCD-aware swizzle: each XCD gets a contiguous chunk = 4 heads' full q range
    const int bid = blockIdx.x;
    const int id  = (bid & 7) * 128 + (bid >> 3);
    const int qb  = id & 31;
    const int bh  = id >> 5;
    const int bb  = bh >> 3, h = bh & 7;
    const int q0  = qb * 64;
    const int NT  = Ln / 64;

    const short* Qp = Qh + (size_t)bh * Ln * DKn;
    const short* Kp = Kh + (size_t)bh * Ln * DKn;
    const short* Vp = Vt + (size_t)bh * DKn * Ln;
    const float* mp = maskF + bb * Ln;

    // Q B-frags (pre-scaled): lane q = q0 + w*32 + q32; dk = 16s + 8hi + j
    bf16x8 qf[4];
    #pragma unroll
    for (int s = 0; s < 4; ++s)
        qf[s] = *(const bf16x8*)&Qp[(size_t)(q0 + w * 32 + q32) * DKn + 16 * s + 8 * hi];

    // all-ones bf16 A-fragment for MFMA row sums
    constexpr short BF1 = (short)0x3F80;
    const bf16x8 ones = {BF1, BF1, BF1, BF1, BF1, BF1, BF1, BF1};

    // ---- staging: thread stages 4 K chunks + 4 V chunks (8 shorts each)
    int sOff[4]; int sRow[4], sC8[4];
    #pragma unroll
    for (int f = 0; f < 4; ++f) {
        int cid = tid + 128 * f;
        sRow[f] = cid >> 3;
        sC8[f]  = cid & 7;
        sOff[f] = sRow[f] * 64 + ((sC8[f] * 8) ^ ((sRow[f] & 7) << 3));
    }

    // ---- fragment read offsets (shared swizzle term)
    const int swz = (q32 & 7) << 3;
    int chunk[4];
    #pragma unroll
    for (int s = 0; s < 4; ++s) chunk[s] = (16 * s + 8 * hi) ^ swz;
    const int fb0 = q32 * 64;                 // rows 0-31 (kc or dk)
    const int fb1 = (32 + q32) * 64;          // rows 32-63
    int pwr[2][4];                            // P write: [m-tile][group]
    #pragma unroll
    for (int m_ = 0; m_ < 2; ++m_)
        #pragma unroll
        for (int gidx = 0; gidx < 4; ++gidx)
            pwr[m_][gidx] = q32 * 64 + ((8 * gidx + 32 * m_) ^ swz) + 4 * hi;

    f32x16 oacc0, oacc1, lsum;
    #pragma unroll
    for (int i = 0; i < 16; ++i) { oacc0[i] = 0.f; oacc1[i] = 0.f; lsum[i] = 0.f; }
    float m_run = -1e30f;

    // ---- prologue: stage tile 0, prefetch tile 1
    bf16x8 krg[4], vrg[4];
    #pragma unroll
    for (int f = 0; f < 4; ++f) {
        krg[f] = *(const bf16x8*)&Kp[(size_t)sRow[f] * DKn + sC8[f] * 8];
        vrg[f] = *(const bf16x8*)&Vp[(size_t)sRow[f] * Ln + sC8[f] * 8];
    }
    #pragma unroll
    for (int f = 0; f < 4; ++f) {
        *(bf16x8*)&Ks[0][sOff[f]] = krg[f];
        *(bf16x8*)&Vs[0][sOff[f]] = vrg[f];
    }
    #pragma unroll
    for (int f = 0; f < 4; ++f) {
        krg[f] = *(const bf16x8*)&Kp[(size_t)(64 + sRow[f]) * DKn + sC8[f] * 8];
        vrg[f] = *(const bf16x8*)&Vp[(size_t)sRow[f] * Ln + 64 + sC8[f] * 8];
    }
    __syncthreads();

    int c = 0;
    for (int t = 0; t < NT; ++t) {
        if (t < NT - 1) {
            #pragma unroll
            for (int f = 0; f < 4; ++f) {
                *(bf16x8*)&Ks[c ^ 1][sOff[f]] = krg[f];
                *(bf16x8*)&Vs[c ^ 1][sOff[f]] = vrg[f];
            }
            int tn = (t + 2 < NT) ? t + 2 : NT - 1;
            #pragma unroll
            for (int f = 0; f < 4; ++f) {
                krg[f] = *(const bf16x8*)&Kp[(size_t)(tn * 64 + sRow[f]) * DKn + sC8[f] * 8];
                vrg[f] = *(const bf16x8*)&Vp[(size_t)sRow[f] * Ln + tn * 64 + sC8[f] * 8];
            }
        }

        // ---- mask (additive f32, L2-resident): kc = (r&3) + 8*(r>>2) + 4hi + 32m
        f32x4 mk0[4], mk1[4];
        #pragma unroll
        for (int gidx = 0; gidx < 4; ++gidx) {
            mk0[gidx] = *(const f32x4*)&mp[t * 64 + 8 * gidx + 4 * hi];
            mk1[gidx] = *(const f32x4*)&mp[t * 64 + 32 + 8 * gidx + 4 * hi];
        }

        // ---- S^T = K Q^T : lane owns q = q32, kc = (r&3)+8*(r>>2)+4hi (+32 for tile 1)
        f32x16 sv0, sv1;
        #pragma unroll
        for (int i = 0; i < 16; ++i) { sv0[i] = 0.f; sv1[i] = 0.f; }
        __builtin_amdgcn_s_setprio(1);
        #pragma unroll
        for (int s = 0; s < 4; ++s) {
            bf16x8 kf = *(const bf16x8*)&Ks[c][fb0 + chunk[s]];
            sv0 = __builtin_amdgcn_mfma_f32_32x32x16_bf16(kf, qf[s], sv0, 0, 0, 0);
        }
        #pragma unroll
        for (int s = 0; s < 4; ++s) {
            bf16x8 kf = *(const bf16x8*)&Ks[c][fb1 + chunk[s]];
            sv1 = __builtin_amdgcn_mfma_f32_32x32x16_bf16(kf, qf[s], sv1, 0, 0, 0);
        }
        __builtin_amdgcn_s_setprio(0);
        #pragma unroll
        for (int r = 0; r < 16; ++r) {
            sv0[r] += mk0[r >> 2][r & 3];
            sv1[r] += mk1[r >> 2][r & 3];
        }

        // ---- defer-max: local 32-max tree; cross-lane reduce only on trigger
        float mt = fmaxf(sv0[0], sv1[0]);
        #pragma unroll
        for (int r = 1; r < 16; ++r) mt = fmaxf(mt, fmaxf(sv0[r], sv1[r]));
        if (!__all(mt <= m_run + 8.0f)) {
            float mtr = fmaxf(mt, __shfl_xor(mt, 32));
            float mnew = fmaxf(m_run, mtr);
            float fac  = exp2f(m_run - mnew);
            m_run = mnew;
            #pragma unroll
            for (int i = 0; i < 16; ++i) { oacc0[i] *= fac; oacc1[i] *= fac; }
            lsum *= fac;
        }

        // ---- P = exp2(S - m) -> packed bf16, wave-private LDS [q][kc] swizzled
        #pragma unroll
        for (int gidx = 0; gidx < 4; ++gidx) {
            float p0 = exp2f(sv0[4 * gidx + 0] - m_run), p1 = exp2f(sv0[4 * gidx + 1] - m_run);
            float p2 = exp2f(sv0[4 * gidx + 2] - m_run), p3 = exp2f(sv0[4 * gidx + 3] - m_run);
            uint2 pk = {cvt_pk_bf16(p0, p1), cvt_pk_bf16(p2, p3)};
            *(uint2*)&Pl[w][pwr[0][gidx]] = pk;
            p0 = exp2f(sv1[4 * gidx + 0] - m_run); p1 = exp2f(sv1[4 * gidx + 1] - m_run);
            p2 = exp2f(sv1[4 * gidx + 2] - m_run); p3 = exp2f(sv1[4 * gidx + 3] - m_run);
            uint2 pk1 = {cvt_pk_bf16(p0, p1), cvt_pk_bf16(p2, p3)};
            *(uint2*)&Pl[w][pwr[1][gidx]] = pk1;
        }

        // ---- O^T += V^T P ; lsum += ones * P  (row sums on the MFMA pipe)
        __builtin_amdgcn_s_setprio(1);
        bf16x8 pf[4];
        #pragma unroll
        for (int s = 0; s < 4; ++s)
            pf[s] = *(const bf16x8*)&Pl[w][q32 * 64 + chunk[s]];
        #pragma unroll
        for (int s = 0; s < 4; ++s)
            lsum = __builtin_amdgcn_mfma_f32_32x32x16_bf16(ones, pf[s], lsum, 0, 0, 0);
        #pragma unroll
        for (int s = 0; s < 4; ++s) {
            bf16x8 vf = *(const bf16x8*)&Vs[c][fb0 + chunk[s]];
            oacc0 = __builtin_amdgcn_mfma_f32_32x32x16_bf16(vf, pf[s], oacc0, 0, 0, 0);
        }
        #pragma unroll
        for (int s = 0; s < 4; ++s) {
            bf16x8 vf = *(const bf16x8*)&Vs[c][fb1 + chunk[s]];
            oacc1 = __builtin_amdgcn_mfma_f32_32x32x16_bf16(vf, pf[s], oacc1, 0, 0, 0);
        }
        __builtin_amdgcn_s_setprio(0);

        __syncthreads();
        c ^= 1;
    }

    // epilogue: lane owns q = q0 + w*32 + q32; dk = d*32 + (r&3)+8*(r>>2)+4hi
    float inv = 1.0f / lsum[0];
    size_t mrow = (size_t)bb * Ln + q0 + w * 32 + q32;
    #pragma unroll
    for (int gidx = 0; gidx < 4; ++gidx) {
        uint2 pr0 = {cvt_pk_bf16(oacc0[4 * gidx + 0] * inv, oacc0[4 * gidx + 1] * inv),
                     cvt_pk_bf16(oacc0[4 * gidx + 2] * inv, oacc0[4 * gidx + 3] * inv)};
        *(uint2*)&Ctx[mrow * Dn + h * 64 + 8 * gidx + 4 * hi] = pr0;
        uint2 pr1 = {cvt_pk_bf16(oacc1[4 * gidx + 0] * inv, oacc1[4 * gidx + 1] * inv),
                     cvt_pk_bf16(oacc1[4 * gidx + 2] * inv, oacc1[4 * gidx + 3] * inv)};
        *(uint2*)&Ctx[mrow * Dn + h * 64 + 32 + 8 * gidx + 4 * hi] = pr1;
    }
}

// ---------------------------------------------------------------------------
// Kernel 3: output projection, bf16 MFMA. grid (Mtot/128, Dn/128), block 256.
// ---------------------------------------------------------------------------
__global__ __launch_bounds__(256) void out_proj_mfma(
    const short* __restrict__ Ctx, const float* __restrict__ W,
    const float* __restrict__ bias, float* __restrict__ Out)
{
    __shared__ short As[128 * 72];
    __shared__ short Bs[128 * 72];

    const int tid  = threadIdx.x;
    const int lane = tid & 63, w = tid >> 6;
    const int wr = w >> 1, wc = w & 1;
    const int l16 = lane & 15, g = lane >> 4;
    const int m0 = blockIdx.x * 128, n0 = blockIdx.y * 128;

    f32x4 acc[4][4];
    #pragma unroll
    for (int i = 0; i < 4; ++i)
        #pragma unroll
        for (int j = 0; j < 4; ++j)
            acc[i][j] = (f32x4){0.f, 0.f, 0.f, 0.f};

    for (int k0 = 0; k0 < Dn; k0 += 64) {
        #pragma unroll
        for (int f = 0; f < 4; ++f) {
            int lin = tid + 256 * f;
            int row = lin >> 3, c8 = lin & 7;
            bf16x8 av = *(const bf16x8*)&Ctx[(size_t)(m0 + row) * Dn + k0 + c8 * 8];
            *(bf16x8*)&As[row * 72 + c8 * 8] = av;
        }
        #pragma unroll
        for (int f = 0; f < 8; ++f) {
            int lin = tid + 256 * f;
            int row = lin >> 4, c4 = lin & 15;
            float4 wv4 = *(const float4*)&W[(size_t)(n0 + row) * Dn + k0 + c4 * 4];
            uint2 wp = {cvt_pk_bf16(wv4.x, wv4.y), cvt_pk_bf16(wv4.z, wv4.w)};
            *(uint2*)&Bs[row * 72 + c4 * 4] = wp;
        }
        __syncthreads();

        bf16x8 af[4][2], bfv[4][2];
        #pragma unroll
        for (int i = 0; i < 4; ++i)
            #pragma unroll
            for (int c = 0; c < 2; ++c)
                af[i][c] = *(const bf16x8*)&As[(wr * 64 + i * 16 + l16) * 72 + c * 32 + g * 8];
        #pragma unroll
        for (int j = 0; j < 4; ++j)
            #pragma unroll
            for (int c = 0; c < 2; ++c)
                bfv[j][c] = *(const bf16x8*)&Bs[(wc * 64 + j * 16 + l16) * 72 + c * 32 + g * 8];

        #pragma unroll
        for (int i = 0; i < 4; ++i)
            #pragma unroll
            for (int j = 0; j < 4; ++j) {
                acc[i][j] = __builtin_amdgcn_mfma_f32_16x16x32_bf16(af[i][0], bfv[j][0], acc[i][j], 0, 0, 0);
                acc[i][j] = __builtin_amdgcn_mfma_f32_16x16x32_bf16(af[i][1], bfv[j][1], acc[i][j], 0, 0, 0);
            }
        __syncthreads();
    }

    #pragma unroll
    for (int i = 0; i < 4; ++i) {
        #pragma unroll
        for (int j = 0; j < 4; ++j) {
            int n = n0 + wc * 64 + j * 16 + l16;
            float bval = bias[n];
            #pragma unroll
            for (int r = 0; r < 4; ++r) {
                int m = m0 + wr * 64 + i * 16 + g * 4 + r;
                Out[(size_t)m * Dn + n] = acc[i][j][r] + bval;
            }
        }
    }
}

// ---------------------------------------------------------------------------
extern "C" void kernel_launch(void* const* d_in, const int* in_sizes, int n_in,
                              void* d_out, int out_size, void* d_ws, size_t ws_size,
                              hipStream_t stream)
{
    (void)in_sizes; (void)n_in; (void)out_size; (void)ws_size;
    const float* q    = (const float*)d_in[0];
    const float* k    = (const float*)d_in[1];
    const float* v    = (const float*)d_in[2];
    const int*   mks  = (const int*)  d_in[3];
    const float* wq_w = (const float*)d_in[4];
    const float* wq_b = (const float*)d_in[5];
    const float* wk_w = (const float*)d_in[6];
    const float* wk_b = (const float*)d_in[7];
    const float* wv_w = (const float*)d_in[8];
    const float* wv_b = (const float*)d_in[9];
    const float* wo_w = (const float*)d_in[10];
    const float* wo_b = (const float*)d_in[11];
    float* out = (float*)d_out;

    const size_t headElems = (size_t)Bn * Hn * Ln * DKn;
    short* ws  = (short*)d_ws;
    short* Qh  = ws;
    short* Kh  = ws + headElems;
    short* Vt  = ws + 2 * headElems;
    short* Ctx = ws + 3 * headElems;
    float* maskF = (float*)(ws + 4 * headElems);

    mask_prep<<<dim3((Bn * Ln + 255) / 256), 256, 0, stream>>>(mks, maskF);

    qkv_proj_mfma<<<dim3(Mtot / 128, Dn / 128, 3), 256, 0, stream>>>(
        q, k, v, wq_w, wk_w, wv_w, wq_b, wk_b, wv_b, Qh, Kh, Vt);

    attn_mfma<<<dim3(1024), 128, 0, stream>>>(Qh, Kh, Vt, maskF, Ctx);

    out_proj_mfma<<<dim3(Mtot / 128, Dn / 128), 256, 0, stream>>>(Ctx, wo_w, wo_b, out);
}